// Round 6
// baseline (211.434 us; speedup 1.0000x reference)
//
#include <hip/hip_runtime.h>

// RandomForest: 131072 samples x 64 feat, 64 trees depth 12, 8-class vote.
//
// R6 theory: R5 is bound by L2->L1 line fills on divergent deep gathers
// (~2 cyc/line, 150 lines/walk; deep levels = 128 of them). Fix: stage each
// tree's deep tables (pair lvl8-9: 256x16B, sub lvl10-11+leaves: 1024x16B,
// 20KiB blob) in LDS; walk one tree at a time (barrier-synced window),
// register-prefetch the next tree's blob during the walk. Shallow pairs
// (lvls 0-7, 1.4KB/tree) stay global = L1-hot, ~22 lines/walk.
// Chain-latency mitigation (R3 lesson): issue all 3 candidate X-reads
// (f0,fL,fR) in parallel per 16B entry.

constexpr int kSamples  = 131072;
constexpr int kFeat     = 64;
constexpr int kTrees    = 64;
constexpr int kInternal = 4095;
constexpr int kClasses  = 8;

constexpr int TPB    = 512;
constexpr int XSTR   = 512;                      // dwords; f column = f<<11 bytes
constexpr int XBYTES = kFeat * XSTR * 4;         // 131072
constexpr int DEEPN  = 1280;                     // 256 pair + 1024 sub entries
constexpr int LDS_BYTES = XBYTES + DEEPN * 16;   // 151552 <= 160 KiB

struct Entry { float thr0, thrL, thrR; unsigned meta; };
// meta: f0 | fL<<6 | fR<<12  (+ for sub entries: lv0..lv3 << 18,21,24,27)

// Shallow pairs p=0..3 (levels 0..7): 85 entries/tree, stride 128.
__global__ __launch_bounds__(256) void pack_shallow_kernel(
    const int* __restrict__ features, const float* __restrict__ thresholds,
    Entry* __restrict__ shal)
{
    int i = blockIdx.x * 256 + threadIdx.x;      // over 64*85
    if (i >= kTrees * 85) return;
    int t = i / 85;
    int e = i - t * 85;
    int p, m;
    if      (e < 1)  { p = 0; m = e; }
    else if (e < 5)  { p = 1; m = e - 1; }
    else if (e < 21) { p = 2; m = e - 5; }
    else             { p = 3; m = e - 21; }
    int g0 = (1 << (2 * p)) - 1 + m;
    int b  = t * kInternal;
    Entry pr;
    pr.thr0 = thresholds[b + g0];
    pr.thrL = thresholds[b + 2 * g0 + 1];
    pr.thrR = thresholds[b + 2 * g0 + 2];
    pr.meta = (unsigned)features[b + g0]
            | ((unsigned)features[b + 2 * g0 + 1] << 6)
            | ((unsigned)features[b + 2 * g0 + 2] << 12);
    shal[(t << 7) + e] = pr;
}

// Deep blob per tree: [0..256) = pair over levels 8,9 ; [256..1280) = sub
// over levels 10,11 + 4 leaf classes. Contiguous 20 KiB for linear staging.
__global__ __launch_bounds__(256) void pack_deep_kernel(
    const int* __restrict__ features, const float* __restrict__ thresholds,
    const int* __restrict__ leaf_values, Entry* __restrict__ deep)
{
    int t = blockIdx.x / 5;                       // 5 blocks of 256 per tree
    int e = (blockIdx.x % 5) * 256 + threadIdx.x; // 0..1279
    int b = t * kInternal;
    Entry pr;
    if (e < 256) {                                // level-8 node + lvl-9 children
        int g0 = 255 + e;
        pr.thr0 = thresholds[b + g0];
        pr.thrL = thresholds[b + 2 * g0 + 1];
        pr.thrR = thresholds[b + 2 * g0 + 2];
        pr.meta = (unsigned)features[b + g0]
                | ((unsigned)features[b + 2 * g0 + 1] << 6)
                | ((unsigned)features[b + 2 * g0 + 2] << 12);
    } else {                                      // level-10 node j, lvl-11 children, leaves
        int j   = e - 256;
        int n10 = 1023 + j;
        pr.thr0 = thresholds[b + n10];
        pr.thrL = thresholds[b + 2 * n10 + 1];
        pr.thrR = thresholds[b + 2 * n10 + 2];
        const int* lv = leaf_values + ((t << 12) + 4 * j);
        pr.meta = (unsigned)features[b + n10]
                | ((unsigned)features[b + 2 * n10 + 1] << 6)
                | ((unsigned)features[b + 2 * n10 + 2] << 12)
                | ((unsigned)lv[0] << 18) | ((unsigned)lv[1] << 21)
                | ((unsigned)lv[2] << 24) | ((unsigned)lv[3] << 27);
    }
    deep[t * DEEPN + e] = pr;
}

__device__ __forceinline__ int step2(const Entry& pr, const char* xb, int m) {
    // All three X reads depend only on pr -> issued in parallel (short chain).
    float x0 = *(const float*)(xb + ((pr.meta & 63u) << 11));
    float xL = *(const float*)(xb + (((pr.meta >> 6) & 63u) << 11));
    float xR = *(const float*)(xb + (((pr.meta >> 12) & 63u) << 11));
    int   c0 = x0 > pr.thr0 ? 1 : 0;
    float t1 = c0 ? pr.thrR : pr.thrL;
    float x1 = c0 ? xR : xL;
    int   c1 = x1 > t1 ? 1 : 0;
    return 4 * m + 2 * c0 + c1;
}

__global__ __launch_bounds__(TPB, 1) void forest_kernel(
    const float* __restrict__ X,
    const Entry* __restrict__ shal,     // [64][128] (85 used)
    const Entry* __restrict__ deep,     // [64][1280]
    int* __restrict__ out)
{
    extern __shared__ float xs[];                   // X tile + deep-tree buf
    float4* __restrict__ buf4 = (float4*)((char*)xs + XBYTES);
    const Entry* __restrict__ ldsDeep = (const Entry*)buf4;

    const int tid  = threadIdx.x;
    const int base = blockIdx.x * TPB;

    // Stage own X row: LDS writes at f*512+tid -> bank=tid%32, 2-way (free).
    {
        const float4* Xr = (const float4*)(X + (size_t)(base + tid) * kFeat);
        #pragma unroll
        for (int k = 0; k < kFeat / 4; ++k) {
            float4 v = Xr[k];
            xs[(4 * k + 0) * XSTR + tid] = v.x;
            xs[(4 * k + 1) * XSTR + tid] = v.y;
            xs[(4 * k + 2) * XSTR + tid] = v.z;
            xs[(4 * k + 3) * XSTR + tid] = v.w;
        }
    }

    const char* xb = (const char*)xs + (tid << 2);
    unsigned long long votes = 0ull;

    const float4* dg = (const float4*)deep;
    // Prefetch tree 0's 20 KiB blob into registers (3 float4/thread).
    float4 pf0 = dg[tid];
    float4 pf1 = dg[tid + 512];
    float4 pf2 = tid < 256 ? dg[tid + 1024] : make_float4(0.f, 0.f, 0.f, 0.f);

    for (int t = 0; t < kTrees; ++t) {
        __syncthreads();                     // prev walk done (also X stage @t=0)
        buf4[tid]       = pf0;
        buf4[tid + 512] = pf1;
        if (tid < 256) buf4[tid + 1024] = pf2;
        __syncthreads();

        if (t + 1 < kTrees) {                // next tree's loads fly during walk
            const float4* dn = dg + (t + 1) * DEEPN;
            pf0 = dn[tid];
            pf1 = dn[tid + 512];
            if (tid < 256) pf2 = dn[tid + 1024];
        }

        // Walk: 4 shallow global gathers (L1-hot 1.4KB table) + 2 LDS gathers.
        const Entry* st = shal + (t << 7);
        int m = 0;
        m = step2(st[m], xb, m);             // lvls 0,1   (m: 0 -> 0..3)
        m = step2(st[1 + m], xb, m);         // lvls 2,3   (-> 0..15)
        m = step2(st[5 + m], xb, m);         // lvls 4,5   (-> 0..63)
        m = step2(st[21 + m], xb, m);        // lvls 6,7   (-> 0..255)
        m = step2(ldsDeep[m], xb, m);        // lvls 8,9   (-> 0..1023)
        Entry sb = ldsDeep[256 + m];         // lvls 10,11 + leaves
        {
            float x0 = *(const float*)(xb + ((sb.meta & 63u) << 11));
            float xL = *(const float*)(xb + (((sb.meta >> 6) & 63u) << 11));
            float xR = *(const float*)(xb + (((sb.meta >> 12) & 63u) << 11));
            int   c0 = x0 > sb.thr0 ? 1 : 0;
            float t1 = c0 ? sb.thrR : sb.thrL;
            float x1 = c0 ? xR : xL;
            int   c1 = x1 > t1 ? 1 : 0;
            int  cls = (sb.meta >> (18 + 3 * ((c0 << 1) | c1))) & 7;
            votes += 1ull << (cls << 3);
        }
    }

    // argmax over 8 packed byte counters; strict '>' keeps smallest class
    int best = 0;
    int bc   = (int)(votes & 0xFFull);
    #pragma unroll
    for (int c = 1; c < kClasses; ++c) {
        int cnt = (int)((votes >> (c * 8)) & 0xFFull);
        if (cnt > bc) { bc = cnt; best = c; }
    }
    out[base + tid] = best;
}

extern "C" void kernel_launch(void* const* d_in, const int* in_sizes, int n_in,
                              void* d_out, int out_size, void* d_ws, size_t ws_size,
                              hipStream_t stream) {
    const float* X          = (const float*)d_in[0];
    const int*   features   = (const int*)d_in[1];
    const float* thresholds = (const float*)d_in[2];
    const int*   leaves     = (const int*)d_in[3];
    int*         out        = (int*)d_out;

    Entry* shal = (Entry*)d_ws;                              // 64*128*16 = 128 KiB
    Entry* deep = (Entry*)((char*)d_ws + (kTrees << 11));    // +128 KiB; 1.25 MiB

    (void)hipFuncSetAttribute((const void*)forest_kernel,
                              hipFuncAttributeMaxDynamicSharedMemorySize,
                              LDS_BYTES);

    pack_shallow_kernel<<<(kTrees * 85 + 255) / 256, 256, 0, stream>>>(
        features, thresholds, shal);
    pack_deep_kernel<<<kTrees * 5, 256, 0, stream>>>(
        features, thresholds, leaves, deep);
    forest_kernel<<<kSamples / TPB, TPB, LDS_BYTES, stream>>>(
        X, shal, deep, out);
}

// Round 7
// 150.369 us; speedup vs baseline: 1.4061x; 1.4061x over previous
//
#include <hip/hip_runtime.h>

// RandomForest: 131072 samples x 64 feat, 64 trees depth 12, 8-class vote.
//
// R7 = R5 (66us: ILP=8 tree chains, 512thr/block, X feature-major in LDS)
// + pair4 (levels 8,9; 4KiB/tree) LDS-staged per 8-tree window (32KiB,
// filling LDS to exactly 160KiB). Theory: R5 is bound by L2->L1 line fills
// (~150 lines/wave-walk ~= 19TB/s aggregate, ~ random-fill ceiling);
// pair4 is ~40 of those lines -> ~27% less line traffic, LDS b128 random
// gather (~35cyc, 8-way conflicts) replaces it off the L2 path.
// R6 lesson kept: never drop tree-ILP; barriers only 2 per window.

constexpr int kSamples  = 131072;
constexpr int kFeat     = 64;
constexpr int kTrees    = 64;
constexpr int kInternal = 4095;
constexpr int kClasses  = 8;

constexpr int TPB    = 512;
constexpr int XSTR   = 512;                      // dwords; f column = f<<11 bytes
constexpr int XBYTES = kFeat * XSTR * 4;         // 131072 B
constexpr int ILP    = 8;
constexpr int P4N    = 256;                      // pair4 entries per tree
constexpr int LDS_BYTES = XBYTES + ILP * P4N * 16;  // 163840 B = 160 KiB exactly

// Pair p covers levels 2p,2p+1; entries-before offsets {0,1,5,21,85}, 341/tree,
// stride 512 -> tree base = t<<9. Entries 85..341 are pair4 (staged to LDS).
struct Pair  { float thr0, thrL, thrR; unsigned meta; };  // meta: f0|fL<<6|fR<<12
struct Sub16 { float thr10, thrL, thrR; unsigned meta; }; // +lv0..lv3 <<18,21,24,27

__global__ __launch_bounds__(256) void pack_pairs_kernel(
    const int* __restrict__ features, const float* __restrict__ thresholds,
    Pair* __restrict__ pairsA)
{
    int i = blockIdx.x * 256 + threadIdx.x;       // over 64*341
    if (i >= kTrees * 341) return;
    int t = i / 341;
    int e = i - t * 341;
    int p, m;
    if      (e < 1)  { p = 0; m = e; }
    else if (e < 5)  { p = 1; m = e - 1; }
    else if (e < 21) { p = 2; m = e - 5; }
    else if (e < 85) { p = 3; m = e - 21; }
    else             { p = 4; m = e - 85; }
    int g0 = (1 << (2 * p)) - 1 + m;              // global node id at level 2p
    int b  = t * kInternal;
    Pair pr;
    pr.thr0 = thresholds[b + g0];
    pr.thrL = thresholds[b + 2 * g0 + 1];
    pr.thrR = thresholds[b + 2 * g0 + 2];
    pr.meta = (unsigned)features[b + g0]
            | ((unsigned)features[b + 2 * g0 + 1] << 6)
            | ((unsigned)features[b + 2 * g0 + 2] << 12);
    pairsA[(t << 9) + e] = pr;
}

__global__ __launch_bounds__(256) void pack_sub_kernel(
    const int* __restrict__ features, const float* __restrict__ thresholds,
    const int* __restrict__ leaf_values, Sub16* __restrict__ subsA)
{
    int i = blockIdx.x * 256 + threadIdx.x;       // over 64*1024
    if (i >= kTrees * 1024) return;
    int t = i >> 10;
    int j = i & 1023;                              // level-10 local index
    int n10 = 1023 + j;
    int b   = t * kInternal;
    Sub16 sb;
    sb.thr10 = thresholds[b + n10];
    sb.thrL  = thresholds[b + 2 * n10 + 1];
    sb.thrR  = thresholds[b + 2 * n10 + 2];
    const int* lv = leaf_values + ((t << 12) + 4 * j);
    sb.meta = (unsigned)features[b + n10]
            | ((unsigned)features[b + 2 * n10 + 1] << 6)
            | ((unsigned)features[b + 2 * n10 + 2] << 12)
            | ((unsigned)lv[0] << 18) | ((unsigned)lv[1] << 21)
            | ((unsigned)lv[2] << 24) | ((unsigned)lv[3] << 27);
    subsA[(t << 10) + j] = sb;
}

__global__ __launch_bounds__(TPB, 1) void forest_kernel(
    const float* __restrict__ X,
    const Pair*  __restrict__ pairsA,   // [64][512] (341 used; 85..341 = pair4)
    const Sub16* __restrict__ subsA,    // [64][1024]
    int* __restrict__ out)
{
    extern __shared__ float xs[];                  // X tile + pair4 window
    float4* __restrict__ p4buf = (float4*)((char*)xs + XBYTES);
    const Pair* __restrict__ ldsP4 = (const Pair*)p4buf;

    const int tid  = threadIdx.x;
    const int base = blockIdx.x * TPB;

    // Stage own X row: LDS writes at f*512+tid -> bank=tid%32, 2-way (free).
    {
        const float4* Xr = (const float4*)(X + (size_t)(base + tid) * kFeat);
        #pragma unroll
        for (int k = 0; k < kFeat / 4; ++k) {
            float4 v = Xr[k];
            xs[(4 * k + 0) * XSTR + tid] = v.x;
            xs[(4 * k + 1) * XSTR + tid] = v.y;
            xs[(4 * k + 2) * XSTR + tid] = v.z;
            xs[(4 * k + 3) * XSTR + tid] = v.w;
        }
    }

    const char* xb = (const char*)xs + (tid << 2); // + (f<<11) per access
    unsigned long long votes = 0ull;

    const int mofs[4] = {0, 1, 5, 21};             // shallow pair offsets

    for (int t0 = 0; t0 < kTrees; t0 += ILP) {
        // Prefetch this window's pair4 tables (8 trees x 256 entries x 16B
        // = 2048 float4; 4 per thread, waves read 4KiB contiguous chunks).
        float4 pf[4];
        #pragma unroll
        for (int k = 0; k < 4; ++k) {
            int idx = k * TPB + tid;               // 0..2047
            int j   = idx >> 8;                    // window tree 0..7
            int m   = idx & 255;
            pf[k] = ((const float4*)(pairsA + ((t0 + j) << 9) + 85))[m];
        }
        __syncthreads();                           // prev window's LDS reads done
        #pragma unroll
        for (int k = 0; k < 4; ++k) p4buf[k * TPB + tid] = pf[k];
        __syncthreads();                           // staging visible

        int m[ILP];
        #pragma unroll
        for (int j = 0; j < ILP; ++j) m[j] = 0;

        #pragma unroll
        for (int p = 0; p < 4; ++p) {              // levels 0..7 (global, L1-hot)
            #pragma unroll
            for (int j = 0; j < ILP; ++j) {
                Pair pr = pairsA[((t0 + j) << 9) + mofs[p] + m[j]];
                float x0 = *(const float*)(xb + ((pr.meta & 63u) << 11));
                int c0 = x0 > pr.thr0 ? 1 : 0;
                float thr1     = c0 ? pr.thrR : pr.thrL;
                unsigned fsel  = c0 ? (pr.meta >> 12) : (pr.meta >> 6);
                float x1 = *(const float*)(xb + ((fsel & 63u) << 11));
                int c1 = x1 > thr1 ? 1 : 0;
                m[j] = 4 * m[j] + 2 * c0 + c1;
            }
        }

        #pragma unroll
        for (int j = 0; j < ILP; ++j) {            // levels 8,9 from LDS
            Pair pr = ldsP4[(j << 8) + m[j]];
            float x0 = *(const float*)(xb + ((pr.meta & 63u) << 11));
            int c0 = x0 > pr.thr0 ? 1 : 0;
            float thr1     = c0 ? pr.thrR : pr.thrL;
            unsigned fsel  = c0 ? (pr.meta >> 12) : (pr.meta >> 6);
            float x1 = *(const float*)(xb + ((fsel & 63u) << 11));
            int c1 = x1 > thr1 ? 1 : 0;
            m[j] = 4 * m[j] + 2 * c0 + c1;
        }

        #pragma unroll
        for (int j = 0; j < ILP; ++j) {            // levels 10,11 + leaf (global)
            Sub16 sb = subsA[((t0 + j) << 10) + m[j]];
            unsigned mt = sb.meta;
            float x0 = *(const float*)(xb + ((mt & 63u) << 11));
            int c0 = x0 > sb.thr10 ? 1 : 0;
            float thr1    = c0 ? sb.thrR : sb.thrL;
            unsigned fsel = c0 ? (mt >> 12) : (mt >> 6);
            float x1 = *(const float*)(xb + ((fsel & 63u) << 11));
            int c1 = x1 > thr1 ? 1 : 0;
            int cls = (mt >> (18 + 3 * ((c0 << 1) | c1))) & 7;
            votes += 1ull << (cls << 3);
        }
    }

    // argmax over 8 packed byte counters; strict '>' keeps smallest class
    int best = 0;
    int bc   = (int)(votes & 0xFFull);
    #pragma unroll
    for (int c = 1; c < kClasses; ++c) {
        int cnt = (int)((votes >> (c * 8)) & 0xFFull);
        if (cnt > bc) { bc = cnt; best = c; }
    }
    out[base + tid] = best;
}

extern "C" void kernel_launch(void* const* d_in, const int* in_sizes, int n_in,
                              void* d_out, int out_size, void* d_ws, size_t ws_size,
                              hipStream_t stream) {
    const float* X          = (const float*)d_in[0];
    const int*   features   = (const int*)d_in[1];
    const float* thresholds = (const float*)d_in[2];
    const int*   leaves     = (const int*)d_in[3];
    int*         out        = (int*)d_out;

    Pair*  pairsA = (Pair*)d_ws;                            // 64*512*16 = 512 KiB
    Sub16* subsA  = (Sub16*)((char*)d_ws + (kTrees << 13)); // +512 KiB, 1 MiB

    (void)hipFuncSetAttribute((const void*)forest_kernel,
                              hipFuncAttributeMaxDynamicSharedMemorySize,
                              LDS_BYTES);

    pack_pairs_kernel<<<(kTrees * 341 + 255) / 256, 256, 0, stream>>>(
        features, thresholds, pairsA);
    pack_sub_kernel<<<(kTrees * 1024 + 255) / 256, 256, 0, stream>>>(
        features, thresholds, leaves, subsA);
    forest_kernel<<<kSamples / TPB, TPB, LDS_BYTES, stream>>>(
        X, pairsA, subsA, out);
}

// Round 8
// 117.615 us; speedup vs baseline: 1.7977x; 1.2785x over previous
//
#include <hip/hip_runtime.h>

// RandomForest: 131072 samples x 64 feat, 64 trees depth 12, 8-class vote.
//
// R8 = R5's walk verbatim (ILP=8 tree chains; pairs lvls0..9 + Sub16
// lvls10,11+leaves; X feature-major XSTR=512 in LDS) with DOUBLED TLP:
// TPB=1024, 2 threads per sample (each walks 32 trees), same 512-sample
// 128 KiB X tile -> 16 waves/CU (4/SIMD) instead of 8. R5's ledger showed
// no pipe saturated (L1 fill 49%, VALU 32%, LDS 23%) at 2 waves/SIMD =>
// latency-bound; more waves should compress toward the L1-fill bound.
// R7 lesson: no register prefetch across barriers (spilled to scratch).

constexpr int kSamples  = 131072;
constexpr int kFeat     = 64;
constexpr int kTrees    = 64;
constexpr int kInternal = 4095;
constexpr int kClasses  = 8;

constexpr int TPB  = 1024;
constexpr int SPB  = 512;                        // samples per block
constexpr int XSTR = 512;                        // dwords; f column = f<<11 bytes
constexpr int XLDS_BYTES = kFeat * XSTR * 4;     // 131072 B
constexpr int ILP  = 8;
constexpr int TREES_PER_THREAD = 32;

// Pair p covers levels 2p,2p+1; entries-before offsets {0,1,5,21,85}, 341/tree,
// stride 512 -> tree base = t<<9.
struct Pair  { float thr0, thrL, thrR; unsigned meta; };  // meta: f0|fL<<6|fR<<12
struct Sub16 { float thr10, thrL, thrR; unsigned meta; }; // +lv0..lv3 <<18,21,24,27

__global__ __launch_bounds__(256) void pack_pairs_kernel(
    const int* __restrict__ features, const float* __restrict__ thresholds,
    Pair* __restrict__ pairsA)
{
    int i = blockIdx.x * 256 + threadIdx.x;       // over 64*341
    if (i >= kTrees * 341) return;
    int t = i / 341;
    int e = i - t * 341;
    int p, m;
    if      (e < 1)  { p = 0; m = e; }
    else if (e < 5)  { p = 1; m = e - 1; }
    else if (e < 21) { p = 2; m = e - 5; }
    else if (e < 85) { p = 3; m = e - 21; }
    else             { p = 4; m = e - 85; }
    int g0 = (1 << (2 * p)) - 1 + m;              // global node id at level 2p
    int b  = t * kInternal;
    Pair pr;
    pr.thr0 = thresholds[b + g0];
    pr.thrL = thresholds[b + 2 * g0 + 1];
    pr.thrR = thresholds[b + 2 * g0 + 2];
    pr.meta = (unsigned)features[b + g0]
            | ((unsigned)features[b + 2 * g0 + 1] << 6)
            | ((unsigned)features[b + 2 * g0 + 2] << 12);
    pairsA[(t << 9) + e] = pr;
}

__global__ __launch_bounds__(256) void pack_sub_kernel(
    const int* __restrict__ features, const float* __restrict__ thresholds,
    const int* __restrict__ leaf_values, Sub16* __restrict__ subsA)
{
    int i = blockIdx.x * 256 + threadIdx.x;       // over 64*1024
    if (i >= kTrees * 1024) return;
    int t = i >> 10;
    int j = i & 1023;                              // level-10 local index
    int n10 = 1023 + j;
    int b   = t * kInternal;
    Sub16 sb;
    sb.thr10 = thresholds[b + n10];
    sb.thrL  = thresholds[b + 2 * n10 + 1];
    sb.thrR  = thresholds[b + 2 * n10 + 2];
    const int* lv = leaf_values + ((t << 12) + 4 * j);
    sb.meta = (unsigned)features[b + n10]
            | ((unsigned)features[b + 2 * n10 + 1] << 6)
            | ((unsigned)features[b + 2 * n10 + 2] << 12)
            | ((unsigned)lv[0] << 18) | ((unsigned)lv[1] << 21)
            | ((unsigned)lv[2] << 24) | ((unsigned)lv[3] << 27);
    subsA[(t << 10) + j] = sb;
}

__global__ __launch_bounds__(TPB, 1) void forest_kernel(
    const float* __restrict__ X,
    const Pair*  __restrict__ pairsA,   // [64][512] (341 used)
    const Sub16* __restrict__ subsA,    // [64][1024]
    int* __restrict__ out)
{
    extern __shared__ float xs[];                  // [64][512] feature-major
    const int tid  = threadIdx.x;
    const int s    = tid & (SPB - 1);              // sample slot 0..511
    const int h    = tid >> 9;                     // forest half 0..1
    const int base = blockIdx.x * SPB;

    // Stage: both threads of a sample each load half its row (8 float4).
    // LDS writes at f*512+s -> bank = s%32, consecutive lanes = 2-way (free).
    {
        const float4* Xr = (const float4*)(X + (size_t)(base + s) * kFeat) + h * 8;
        #pragma unroll
        for (int k = 0; k < 8; ++k) {
            float4 v = Xr[k];
            int f0 = (h * 8 + k) * 4;
            xs[(f0 + 0) * XSTR + s] = v.x;
            xs[(f0 + 1) * XSTR + s] = v.y;
            xs[(f0 + 2) * XSTR + s] = v.z;
            xs[(f0 + 3) * XSTR + s] = v.w;
        }
    }
    __syncthreads();

    const char* xb = (const char*)xs + (s << 2);   // + (f<<11) per access
    unsigned long long votes = 0ull;

    const int mofs[4] = {0, 1, 5, 21};             // shallow pair offsets

    const int tbeg = h * TREES_PER_THREAD;
    for (int t0 = tbeg; t0 < tbeg + TREES_PER_THREAD; t0 += ILP) {
        int m[ILP];
        #pragma unroll
        for (int j = 0; j < ILP; ++j) m[j] = 0;

        #pragma unroll
        for (int p = 0; p < 4; ++p) {              // levels 0..7
            #pragma unroll
            for (int j = 0; j < ILP; ++j) {        // 8 independent chains
                Pair pr = pairsA[((t0 + j) << 9) + mofs[p] + m[j]];
                float x0 = *(const float*)(xb + ((pr.meta & 63u) << 11));
                int c0 = x0 > pr.thr0 ? 1 : 0;
                float thr1     = c0 ? pr.thrR : pr.thrL;
                unsigned fsel  = c0 ? (pr.meta >> 12) : (pr.meta >> 6);
                float x1 = *(const float*)(xb + ((fsel & 63u) << 11));
                int c1 = x1 > thr1 ? 1 : 0;
                m[j] = 4 * m[j] + 2 * c0 + c1;
            }
        }

        #pragma unroll
        for (int j = 0; j < ILP; ++j) {            // levels 8,9 (pair4, global)
            Pair pr = pairsA[((t0 + j) << 9) + 85 + m[j]];
            float x0 = *(const float*)(xb + ((pr.meta & 63u) << 11));
            int c0 = x0 > pr.thr0 ? 1 : 0;
            float thr1     = c0 ? pr.thrR : pr.thrL;
            unsigned fsel  = c0 ? (pr.meta >> 12) : (pr.meta >> 6);
            float x1 = *(const float*)(xb + ((fsel & 63u) << 11));
            int c1 = x1 > thr1 ? 1 : 0;
            m[j] = 4 * m[j] + 2 * c0 + c1;
        }

        #pragma unroll
        for (int j = 0; j < ILP; ++j) {            // levels 10,11 + leaf
            Sub16 sb = subsA[((t0 + j) << 10) + m[j]];
            unsigned mt = sb.meta;
            float x0 = *(const float*)(xb + ((mt & 63u) << 11));
            int c0 = x0 > sb.thr10 ? 1 : 0;
            float thr1    = c0 ? sb.thrR : sb.thrL;
            unsigned fsel = c0 ? (mt >> 12) : (mt >> 6);
            float x1 = *(const float*)(xb + ((fsel & 63u) << 11));
            int c1 = x1 > thr1 ? 1 : 0;
            int cls = (mt >> (18 + 3 * ((c0 << 1) | c1))) & 7;
            votes += 1ull << (cls << 3);
        }
    }

    // Combine the two half-forest vote vectors through LDS (xs is dead now).
    __syncthreads();
    unsigned long long* vbuf = (unsigned long long*)xs;
    if (h == 1) vbuf[s] = votes;
    __syncthreads();
    if (h == 0) {
        votes += vbuf[s];
        // argmax over 8 packed byte counters; strict '>' keeps smallest class
        int best = 0;
        int bc   = (int)(votes & 0xFFull);
        #pragma unroll
        for (int c = 1; c < kClasses; ++c) {
            int cnt = (int)((votes >> (c * 8)) & 0xFFull);
            if (cnt > bc) { bc = cnt; best = c; }
        }
        out[base + s] = best;
    }
}

extern "C" void kernel_launch(void* const* d_in, const int* in_sizes, int n_in,
                              void* d_out, int out_size, void* d_ws, size_t ws_size,
                              hipStream_t stream) {
    const float* X          = (const float*)d_in[0];
    const int*   features   = (const int*)d_in[1];
    const float* thresholds = (const float*)d_in[2];
    const int*   leaves     = (const int*)d_in[3];
    int*         out        = (int*)d_out;

    Pair*  pairsA = (Pair*)d_ws;                            // 64*512*16 = 512 KiB
    Sub16* subsA  = (Sub16*)((char*)d_ws + (kTrees << 13)); // +512 KiB, 1 MiB

    (void)hipFuncSetAttribute((const void*)forest_kernel,
                              hipFuncAttributeMaxDynamicSharedMemorySize,
                              XLDS_BYTES);

    pack_pairs_kernel<<<(kTrees * 341 + 255) / 256, 256, 0, stream>>>(
        features, thresholds, pairsA);
    pack_sub_kernel<<<(kTrees * 1024 + 255) / 256, 256, 0, stream>>>(
        features, thresholds, leaves, subsA);
    forest_kernel<<<kSamples / SPB, TPB, XLDS_BYTES, stream>>>(
        X, pairsA, subsA, out);
}

// Round 9
// 117.497 us; speedup vs baseline: 1.7995x; 1.0010x over previous
//
#include <hip/hip_runtime.h>

// RandomForest: 131072 samples x 64 feat, 64 trees depth 12, 8-class vote.
//
// R9 = R8's walk verbatim, occupancy pushed to the hardware cap:
// 256 samples/block (64 KiB X tile), TPB=1024, 4 threads/sample (16 trees
// each = 2 ILP-8 windows), grid=512 -> 2 blocks/CU -> 32 waves/CU (8/SIMD).
// R8 confirmed latency-bound scaling: 8->16 waves/CU gave 66->48us with
// L1-fill (~77k cyc) and VALU (~52k cyc) both unsaturated. This doubles
// TLP again with the instruction stream unchanged.

constexpr int kSamples  = 131072;
constexpr int kFeat     = 64;
constexpr int kTrees    = 64;
constexpr int kInternal = 4095;
constexpr int kClasses  = 8;

constexpr int TPB  = 1024;
constexpr int SPB  = 256;                        // samples per block
constexpr int XSTR = 256;                        // dwords; f column = f<<10 bytes
constexpr int XLDS_BYTES = kFeat * XSTR * 4;     // 65536 B
constexpr int ILP  = 8;
constexpr int TREES_PER_THREAD = 16;             // 4 thread-slices per sample

// Pair p covers levels 2p,2p+1; entries-before offsets {0,1,5,21,85}, 341/tree,
// stride 512 -> tree base = t<<9.
struct Pair  { float thr0, thrL, thrR; unsigned meta; };  // meta: f0|fL<<6|fR<<12
struct Sub16 { float thr10, thrL, thrR; unsigned meta; }; // +lv0..lv3 <<18,21,24,27

__global__ __launch_bounds__(256) void pack_pairs_kernel(
    const int* __restrict__ features, const float* __restrict__ thresholds,
    Pair* __restrict__ pairsA)
{
    int i = blockIdx.x * 256 + threadIdx.x;       // over 64*341
    if (i >= kTrees * 341) return;
    int t = i / 341;
    int e = i - t * 341;
    int p, m;
    if      (e < 1)  { p = 0; m = e; }
    else if (e < 5)  { p = 1; m = e - 1; }
    else if (e < 21) { p = 2; m = e - 5; }
    else if (e < 85) { p = 3; m = e - 21; }
    else             { p = 4; m = e - 85; }
    int g0 = (1 << (2 * p)) - 1 + m;              // global node id at level 2p
    int b  = t * kInternal;
    Pair pr;
    pr.thr0 = thresholds[b + g0];
    pr.thrL = thresholds[b + 2 * g0 + 1];
    pr.thrR = thresholds[b + 2 * g0 + 2];
    pr.meta = (unsigned)features[b + g0]
            | ((unsigned)features[b + 2 * g0 + 1] << 6)
            | ((unsigned)features[b + 2 * g0 + 2] << 12);
    pairsA[(t << 9) + e] = pr;
}

__global__ __launch_bounds__(256) void pack_sub_kernel(
    const int* __restrict__ features, const float* __restrict__ thresholds,
    const int* __restrict__ leaf_values, Sub16* __restrict__ subsA)
{
    int i = blockIdx.x * 256 + threadIdx.x;       // over 64*1024
    if (i >= kTrees * 1024) return;
    int t = i >> 10;
    int j = i & 1023;                              // level-10 local index
    int n10 = 1023 + j;
    int b   = t * kInternal;
    Sub16 sb;
    sb.thr10 = thresholds[b + n10];
    sb.thrL  = thresholds[b + 2 * n10 + 1];
    sb.thrR  = thresholds[b + 2 * n10 + 2];
    const int* lv = leaf_values + ((t << 12) + 4 * j);
    sb.meta = (unsigned)features[b + n10]
            | ((unsigned)features[b + 2 * n10 + 1] << 6)
            | ((unsigned)features[b + 2 * n10 + 2] << 12)
            | ((unsigned)lv[0] << 18) | ((unsigned)lv[1] << 21)
            | ((unsigned)lv[2] << 24) | ((unsigned)lv[3] << 27);
    subsA[(t << 10) + j] = sb;
}

__global__ __launch_bounds__(TPB, 8) void forest_kernel(
    const float* __restrict__ X,
    const Pair*  __restrict__ pairsA,   // [64][512] (341 used)
    const Sub16* __restrict__ subsA,    // [64][1024]
    int* __restrict__ out)
{
    extern __shared__ float xs[];                  // [64][256] feature-major
    const int tid  = threadIdx.x;
    const int s    = tid & (SPB - 1);              // sample slot 0..255
    const int h    = tid >> 8;                     // forest quarter 0..3
    const int base = blockIdx.x * SPB;

    // Stage: 4 threads per sample each load a quarter-row (4 float4).
    // LDS writes at f*256+s -> bank = s%32, consecutive lanes = 2-way (free).
    {
        const float4* Xr = (const float4*)(X + (size_t)(base + s) * kFeat) + h * 4;
        #pragma unroll
        for (int k = 0; k < 4; ++k) {
            float4 v = Xr[k];
            int f0 = (h * 4 + k) * 4;
            xs[(f0 + 0) * XSTR + s] = v.x;
            xs[(f0 + 1) * XSTR + s] = v.y;
            xs[(f0 + 2) * XSTR + s] = v.z;
            xs[(f0 + 3) * XSTR + s] = v.w;
        }
    }
    __syncthreads();

    const char* xb = (const char*)xs + (s << 2);   // + (f<<10) per access
    unsigned long long votes = 0ull;

    const int mofs[4] = {0, 1, 5, 21};             // shallow pair offsets

    const int tbeg = h * TREES_PER_THREAD;
    for (int t0 = tbeg; t0 < tbeg + TREES_PER_THREAD; t0 += ILP) {
        int m[ILP];
        #pragma unroll
        for (int j = 0; j < ILP; ++j) m[j] = 0;

        #pragma unroll
        for (int p = 0; p < 4; ++p) {              // levels 0..7
            #pragma unroll
            for (int j = 0; j < ILP; ++j) {        // 8 independent chains
                Pair pr = pairsA[((t0 + j) << 9) + mofs[p] + m[j]];
                float x0 = *(const float*)(xb + ((pr.meta & 63u) << 10));
                int c0 = x0 > pr.thr0 ? 1 : 0;
                float thr1     = c0 ? pr.thrR : pr.thrL;
                unsigned fsel  = c0 ? (pr.meta >> 12) : (pr.meta >> 6);
                float x1 = *(const float*)(xb + ((fsel & 63u) << 10));
                int c1 = x1 > thr1 ? 1 : 0;
                m[j] = 4 * m[j] + 2 * c0 + c1;
            }
        }

        #pragma unroll
        for (int j = 0; j < ILP; ++j) {            // levels 8,9 (pair4)
            Pair pr = pairsA[((t0 + j) << 9) + 85 + m[j]];
            float x0 = *(const float*)(xb + ((pr.meta & 63u) << 10));
            int c0 = x0 > pr.thr0 ? 1 : 0;
            float thr1     = c0 ? pr.thrR : pr.thrL;
            unsigned fsel  = c0 ? (pr.meta >> 12) : (pr.meta >> 6);
            float x1 = *(const float*)(xb + ((fsel & 63u) << 10));
            int c1 = x1 > thr1 ? 1 : 0;
            m[j] = 4 * m[j] + 2 * c0 + c1;
        }

        #pragma unroll
        for (int j = 0; j < ILP; ++j) {            // levels 10,11 + leaf
            Sub16 sb = subsA[((t0 + j) << 10) + m[j]];
            unsigned mt = sb.meta;
            float x0 = *(const float*)(xb + ((mt & 63u) << 10));
            int c0 = x0 > sb.thr10 ? 1 : 0;
            float thr1    = c0 ? sb.thrR : sb.thrL;
            unsigned fsel = c0 ? (mt >> 12) : (mt >> 6);
            float x1 = *(const float*)(xb + ((fsel & 63u) << 10));
            int c1 = x1 > thr1 ? 1 : 0;
            int cls = (mt >> (18 + 3 * ((c0 << 1) | c1))) & 7;
            votes += 1ull << (cls << 3);
        }
    }

    // Combine 4 partial vote vectors per sample through LDS (xs dead now).
    __syncthreads();
    unsigned long long* vbuf = (unsigned long long*)xs;   // 3*256 u64 = 6 KiB
    if (h != 0) vbuf[(h - 1) * SPB + s] = votes;
    __syncthreads();
    if (h == 0) {
        votes += vbuf[s] + vbuf[SPB + s] + vbuf[2 * SPB + s];
        // argmax over 8 packed byte counters; strict '>' keeps smallest class
        int best = 0;
        int bc   = (int)(votes & 0xFFull);
        #pragma unroll
        for (int c = 1; c < kClasses; ++c) {
            int cnt = (int)((votes >> (c * 8)) & 0xFFull);
            if (cnt > bc) { bc = cnt; best = c; }
        }
        out[base + s] = best;
    }
}

extern "C" void kernel_launch(void* const* d_in, const int* in_sizes, int n_in,
                              void* d_out, int out_size, void* d_ws, size_t ws_size,
                              hipStream_t stream) {
    const float* X          = (const float*)d_in[0];
    const int*   features   = (const int*)d_in[1];
    const float* thresholds = (const float*)d_in[2];
    const int*   leaves     = (const int*)d_in[3];
    int*         out        = (int*)d_out;

    Pair*  pairsA = (Pair*)d_ws;                            // 64*512*16 = 512 KiB
    Sub16* subsA  = (Sub16*)((char*)d_ws + (kTrees << 13)); // +512 KiB, 1 MiB

    (void)hipFuncSetAttribute((const void*)forest_kernel,
                              hipFuncAttributeMaxDynamicSharedMemorySize,
                              XLDS_BYTES);

    pack_pairs_kernel<<<(kTrees * 341 + 255) / 256, 256, 0, stream>>>(
        features, thresholds, pairsA);
    pack_sub_kernel<<<(kTrees * 1024 + 255) / 256, 256, 0, stream>>>(
        features, thresholds, leaves, subsA);
    forest_kernel<<<kSamples / SPB, TPB, XLDS_BYTES, stream>>>(
        X, pairsA, subsA, out);
}